// Round 18
// baseline (344.507 us; speedup 1.0000x reference)
//
#include <hip/hip_runtime.h>

#define N_NODES_C 100000
#define N_EDGES_C 1600000
#define IN_F 64
#define OUT_F 64
#define NK 4
#define SCAN_BLK 256
#define NBLK ((N_NODES_C + SCAN_BLK - 1) / SCAN_BLK)   // 391
#define EBLK (N_EDGES_C / 256)                         // 6250 exact
#define CPAD 16                                        // cursor stride: 1 per 64B line
#define NSLICE 8
#define SLICE_N (N_NODES_C / NSLICE)                   // 12500 exact
#define SCAT_GRID 2048                                 // 256 blocks per slice

__device__ __forceinline__ unsigned int f2bf(float x) {
    unsigned int u = __float_as_uint(x);
    return (u + 0x7fffu + ((u >> 16) & 1u)) >> 16;
}
__device__ __forceinline__ float bflo(unsigned int u) { return __uint_as_float(u << 16); }
__device__ __forceinline__ float bfhi(unsigned int u) { return __uint_as_float(u & 0xffff0000u); }

// ---------------------------------------------------------------------------
// hist: 1-pass, edge-parallel, fire-and-forget atomics (no slicing — the
// writeback volume is the same either way; slicing only helps RETURNED atomics)
// ---------------------------------------------------------------------------
__global__ __launch_bounds__(256) void hist_kernel(
    const int* __restrict__ dst, int* __restrict__ cnt)
{
    const int e = blockIdx.x * 256 + threadIdx.x;
    if (e < N_EDGES_C) atomicAdd(&cnt[dst[e]], 1);
}

// ---------------------------------------------------------------------------
// proj: standalone (R15 4-node variant — allocates sanely when alone)
// ---------------------------------------------------------------------------
__global__ __launch_bounds__(256, 2) void proj_kernel(
    const float* __restrict__ feat, const float* __restrict__ W,
    unsigned short* __restrict__ hb, int n_nodes)
{
    __shared__ float frow[4][IN_F];
    const int t = threadIdx.x;
    const int o = t >> 2;
    const int k = t & 3;
    float wreg[IN_F];
    {
        const float4* W4 = reinterpret_cast<const float4*>(W + (size_t)(k * OUT_F + o) * IN_F);
        #pragma unroll
        for (int i = 0; i < IN_F / 4; ++i) {
            float4 v = W4[i];
            wreg[4*i+0] = v.x; wreg[4*i+1] = v.y; wreg[4*i+2] = v.z; wreg[4*i+3] = v.w;
        }
    }
    const int nn4 = n_nodes >> 2;   // 25000
    for (int q = blockIdx.x; q < nn4; q += gridDim.x) {
        const int n0 = q << 2;
        if (t < 64) {
            float4 v = reinterpret_cast<const float4*>(feat + (size_t)n0 * IN_F)[t];
            reinterpret_cast<float4*>(frow[t >> 4])[t & 15] = v;
        }
        __syncthreads();
        const float4* f0 = reinterpret_cast<const float4*>(frow[0]);
        const float4* f1 = reinterpret_cast<const float4*>(frow[1]);
        const float4* f2 = reinterpret_cast<const float4*>(frow[2]);
        const float4* f3 = reinterpret_cast<const float4*>(frow[3]);
        float a0 = 0.f, a1 = 0.f, a2 = 0.f, a3 = 0.f;
        #pragma unroll
        for (int i = 0; i < IN_F / 4; ++i) {
            const float4 v0 = f0[i], v1 = f1[i], v2 = f2[i], v3 = f3[i];
            const float w0 = wreg[4*i], w1 = wreg[4*i+1], w2 = wreg[4*i+2], w3 = wreg[4*i+3];
            a0 = fmaf(v0.x,w0, fmaf(v0.y,w1, fmaf(v0.z,w2, fmaf(v0.w,w3, a0))));
            a1 = fmaf(v1.x,w0, fmaf(v1.y,w1, fmaf(v1.z,w2, fmaf(v1.w,w3, a1))));
            a2 = fmaf(v2.x,w0, fmaf(v2.y,w1, fmaf(v2.z,w2, fmaf(v2.w,w3, a2))));
            a3 = fmaf(v3.x,w0, fmaf(v3.y,w1, fmaf(v3.z,w2, fmaf(v3.w,w3, a3))));
        }
        hb[(size_t)(n0+0) * 256 + t] = (unsigned short)f2bf(a0);
        hb[(size_t)(n0+1) * 256 + t] = (unsigned short)f2bf(a1);
        hb[(size_t)(n0+2) * 256 + t] = (unsigned short)f2bf(a2);
        hb[(size_t)(n0+3) * 256 + t] = (unsigned short)f2bf(a3);
        __syncthreads();
    }
}

// ---------------------------------------------------------------------------
// scan1: per-block sums of cnt
// ---------------------------------------------------------------------------
__global__ __launch_bounds__(256) void scan1_kernel(
    const int* __restrict__ cnt, int* __restrict__ bsum)
{
    __shared__ int s[SCAN_BLK];
    int i = blockIdx.x * SCAN_BLK + threadIdx.x;
    int v = (i < N_NODES_C) ? cnt[i] : 0;
    s[threadIdx.x] = v; __syncthreads();
    for (int off = SCAN_BLK / 2; off > 0; off >>= 1) {
        if (threadIdx.x < off) s[threadIdx.x] += s[threadIdx.x + off];
        __syncthreads();
    }
    if (threadIdx.x == 0) bsum[blockIdx.x] = s[0];
}

// ---------------------------------------------------------------------------
// scan23: block-prefix over bsum + local exclusive scan -> row_start,
// padded cursor (one counter per 64B line)
// ---------------------------------------------------------------------------
__global__ __launch_bounds__(256) void scan23_kernel(
    const int* __restrict__ cnt, const int* __restrict__ bsum,
    int* __restrict__ row_start, int* __restrict__ cursor_pad)
{
    __shared__ int pre[SCAN_BLK];
    __shared__ int s[SCAN_BLK];
    const int t = threadIdx.x;
    int p = 0;
    for (int i = t; i < (int)blockIdx.x; i += SCAN_BLK) p += bsum[i];
    pre[t] = p; __syncthreads();
    for (int off = SCAN_BLK / 2; off > 0; off >>= 1) {
        if (t < off) pre[t] += pre[t + off];
        __syncthreads();
    }
    const int boff = pre[0];
    const int i = blockIdx.x * SCAN_BLK + t;
    int v = (i < N_NODES_C) ? cnt[i] : 0;
    s[t] = v; __syncthreads();
    for (int off = 1; off < SCAN_BLK; off <<= 1) {
        int x = (t >= off) ? s[t - off] : 0;
        __syncthreads();
        s[t] += x;
        __syncthreads();
    }
    if (i < N_NODES_C) {
        int ex = s[t] - v + boff;
        row_start[i] = ex;
        cursor_pad[(size_t)i * CPAD] = ex;
        if (i == N_NODES_C - 1) row_start[N_NODES_C] = ex + v;
    }
}

// ---------------------------------------------------------------------------
// scatter (gauss fused, XCD-sliced): block b handles dst-slice b&7; computes
// g for matching lanes, cursor atomic + 16B rec store stay XCD-local.
// ---------------------------------------------------------------------------
__global__ __launch_bounds__(256) void scatter_kernel(
    const int* __restrict__ src, const int* __restrict__ dst,
    const float* __restrict__ pseudo, const float* __restrict__ mu,
    const float* __restrict__ inv_sigma, int* __restrict__ cursor_pad,
    uint4* __restrict__ rec)
{
    float mm[NK*3], ss[NK*3];
    #pragma unroll
    for (int i = 0; i < NK*3; ++i) { mm[i] = mu[i]; ss[i] = inv_sigma[i]; }
    const int slice = (int)blockIdx.x & 7;
    const int w     = (int)blockIdx.x >> 3;          // 0..255 within slice
    const int lo = slice * SLICE_N, hi = lo + SLICE_N;
    for (int c = w; c < EBLK; c += SCAT_GRID / NSLICE) {
        const int e = c * 256 + (int)threadIdx.x;
        const int d = dst[e];
        if (d >= lo && d < hi) {
            const float p0 = pseudo[(size_t)e * 3 + 0];
            const float p1 = pseudo[(size_t)e * 3 + 1];
            const float p2 = pseudo[(size_t)e * 3 + 2];
            float g[NK];
            #pragma unroll
            for (int k = 0; k < NK; ++k) {
                const float d0 = p0 - mm[k*3+0], d1 = p1 - mm[k*3+1], d2 = p2 - mm[k*3+2];
                const float s0 = ss[k*3+0], s1 = ss[k*3+1], s2 = ss[k*3+2];
                g[k] = __expf(-0.5f * (d0*d0*s0*s0 + d1*d1*s1*s1 + d2*d2*s2*s2));
            }
            const int pos = atomicAdd(&cursor_pad[(size_t)d * CPAD], 1);
            uint4 r;
            r.x = (unsigned int)src[e];
            r.y = f2bf(g[0]) | (f2bf(g[1]) << 16);
            r.z = f2bf(g[2]) | (f2bf(g[3]) << 16);
            r.w = 0u;
            rec[pos] = r;
        }
    }
}

// ---------------------------------------------------------------------------
// gather: one wave per dst node (pipelined; at structural floor:
// 400MB L2-miss traffic mandatory = 8 XCD x 51.2MB hb at ~3.65 TB/s fabric)
// ---------------------------------------------------------------------------
__global__ __launch_bounds__(256, 2) void gather_kernel(
    const int* __restrict__ row_start, const uint4* __restrict__ rec,
    const unsigned short* __restrict__ hb,
    const float* __restrict__ feat, const float* __restrict__ bias,
    float* __restrict__ out, int n_nodes)
{
    const int lane = threadIdx.x & 63;
    const int v = (blockIdx.x * 256 + threadIdx.x) >> 6;
    if (v >= n_nodes) return;
    const int r0 = row_start[v];
    const int r1 = row_start[v + 1];
    float acc = 0.f;
    int j = r0;
    const int jend4 = r0 + ((r1 - r0) & ~3);
    if (j < jend4) {
        uint4 a0 = rec[j+0], a1 = rec[j+1], a2 = rec[j+2], a3 = rec[j+3];
        j += 4;
        for (; j < jend4; j += 4) {
            const uint2 h0 = *(const uint2*)(hb + (size_t)a0.x * 256 + lane * 4);
            const uint2 h1 = *(const uint2*)(hb + (size_t)a1.x * 256 + lane * 4);
            const uint2 h2 = *(const uint2*)(hb + (size_t)a2.x * 256 + lane * 4);
            const uint2 h3 = *(const uint2*)(hb + (size_t)a3.x * 256 + lane * 4);
            const uint4 b0 = rec[j+0], b1 = rec[j+1], b2 = rec[j+2], b3 = rec[j+3];
            acc += bflo(a0.y)*bflo(h0.x) + bfhi(a0.y)*bfhi(h0.x)
                 + bflo(a0.z)*bflo(h0.y) + bfhi(a0.z)*bfhi(h0.y);
            acc += bflo(a1.y)*bflo(h1.x) + bfhi(a1.y)*bfhi(h1.x)
                 + bflo(a1.z)*bflo(h1.y) + bfhi(a1.z)*bfhi(h1.y);
            acc += bflo(a2.y)*bflo(h2.x) + bfhi(a2.y)*bfhi(h2.x)
                 + bflo(a2.z)*bflo(h2.y) + bfhi(a2.z)*bfhi(h2.y);
            acc += bflo(a3.y)*bflo(h3.x) + bfhi(a3.y)*bfhi(h3.x)
                 + bflo(a3.z)*bflo(h3.y) + bfhi(a3.z)*bfhi(h3.y);
            a0 = b0; a1 = b1; a2 = b2; a3 = b3;
        }
        {
            const uint2 h0 = *(const uint2*)(hb + (size_t)a0.x * 256 + lane * 4);
            const uint2 h1 = *(const uint2*)(hb + (size_t)a1.x * 256 + lane * 4);
            const uint2 h2 = *(const uint2*)(hb + (size_t)a2.x * 256 + lane * 4);
            const uint2 h3 = *(const uint2*)(hb + (size_t)a3.x * 256 + lane * 4);
            acc += bflo(a0.y)*bflo(h0.x) + bfhi(a0.y)*bfhi(h0.x)
                 + bflo(a0.z)*bflo(h0.y) + bfhi(a0.z)*bfhi(h0.y);
            acc += bflo(a1.y)*bflo(h1.x) + bfhi(a1.y)*bfhi(h1.x)
                 + bflo(a1.z)*bflo(h1.y) + bfhi(a1.z)*bfhi(h1.y);
            acc += bflo(a2.y)*bflo(h2.x) + bfhi(a2.y)*bfhi(h2.x)
                 + bflo(a2.z)*bflo(h2.y) + bfhi(a2.z)*bfhi(h2.y);
            acc += bflo(a3.y)*bflo(h3.x) + bfhi(a3.y)*bfhi(h3.x)
                 + bflo(a3.z)*bflo(h3.y) + bfhi(a3.z)*bfhi(h3.y);
        }
    }
    for (; j < r1; ++j) {
        const uint4 ra = rec[j];
        const uint2 ha = *(const uint2*)(hb + (size_t)ra.x * 256 + lane * 4);
        acc += bflo(ra.y)*bflo(ha.x) + bfhi(ra.y)*bfhi(ha.x)
             + bflo(ra.z)*bflo(ha.y) + bfhi(ra.z)*bfhi(ha.y);
    }
    out[(size_t)v * OUT_F + lane] = acc + feat[(size_t)v * OUT_F + lane] + bias[lane];
}

extern "C" void kernel_launch(void* const* d_in, const int* in_sizes, int n_in,
                              void* d_out, int out_size, void* d_ws, size_t ws_size,
                              hipStream_t stream) {
    const float* feat      = (const float*)d_in[0];
    const float* pseudo    = (const float*)d_in[1];
    const int*   src       = (const int*)d_in[2];
    const int*   dst       = (const int*)d_in[3];
    const float* W_fc      = (const float*)d_in[4];
    const float* mu        = (const float*)d_in[5];
    const float* inv_sigma = (const float*)d_in[6];
    const float* bias      = (const float*)d_in[7];
    float* out = (float*)d_out;

    char* ws = (char*)d_ws;
    unsigned short* hb = (unsigned short*)ws;  ws += (size_t)N_NODES_C * 256 * 2;     // 51.2 MB
    uint4* rec         = (uint4*)ws;           ws += (size_t)N_EDGES_C * 16;          // 25.6 MB
    int* cursor_pad    = (int*)ws;             ws += (size_t)N_NODES_C * CPAD * 4;    // 6.4 MB
    int* cnt           = (int*)ws;             ws += (size_t)N_NODES_C * 4;           // 0.4 MB
    int* row_start     = (int*)ws;             ws += (size_t)(N_NODES_C + 4) * 4;     // 0.4 MB
    int* bsum          = (int*)ws;             ws += 512 * 4;

    hipMemsetAsync(cnt, 0, (size_t)N_NODES_C * 4, stream);
    hist_kernel<<<EBLK, 256, 0, stream>>>(dst, cnt);
    proj_kernel<<<2048, 256, 0, stream>>>(feat, W_fc, hb, N_NODES_C);
    scan1_kernel<<<NBLK, SCAN_BLK, 0, stream>>>(cnt, bsum);
    scan23_kernel<<<NBLK, SCAN_BLK, 0, stream>>>(cnt, bsum, row_start, cursor_pad);
    scatter_kernel<<<SCAT_GRID, 256, 0, stream>>>(src, dst, pseudo, mu, inv_sigma,
                                                  cursor_pad, rec);
    gather_kernel<<<(N_NODES_C * 64 + 255) / 256, 256, 0, stream>>>(
        row_start, rec, hb, feat, bias, out, N_NODES_C);
}

// Round 19
// 321.024 us; speedup vs baseline: 1.0732x; 1.0732x over previous
//
#include <hip/hip_runtime.h>

#define N_NODES_C 100000
#define N_EDGES_C 1600000
#define IN_F 64
#define OUT_F 64
#define NK 4
#define SCAN_BLK 256
#define NBLK ((N_NODES_C + SCAN_BLK - 1) / SCAN_BLK)   // 391
#define EBLK (N_EDGES_C / 256)                         // 6250 exact
#define CPAD 16                                        // cursor stride: 1 per 64B line
#define NSLICE 8
#define SLICE_N (N_NODES_C / NSLICE)                   // 12500 exact
#define SCAT_GRID 2048                                 // 256 blocks per slice

__device__ __forceinline__ unsigned int f2bf(float x) {
    unsigned int u = __float_as_uint(x);
    return (u + 0x7fffu + ((u >> 16) & 1u)) >> 16;
}
__device__ __forceinline__ float bflo(unsigned int u) { return __uint_as_float(u << 16); }
__device__ __forceinline__ float bfhi(unsigned int u) { return __uint_as_float(u & 0xffff0000u); }

// ---------------------------------------------------------------------------
// proj_hist: sequential phases in ONE kernel (R17 champion structure).
// Phase A: 1-pass grid-stride fire-and-forget hist (slicing removed — it only
//          helps RETURNED atomics; fire-and-forget never needed it, and the
//          8x sweep cost 8x dst reads + 8x predicated atomic issue).
// Phase B: proj, 4 nodes/iter, float4 LDS reads, scalar wreg[64].
// ---------------------------------------------------------------------------
__global__ __launch_bounds__(256, 2) void proj_hist_kernel(
    const int* __restrict__ dst, int* __restrict__ cnt,
    const float* __restrict__ feat, const float* __restrict__ W,
    unsigned short* __restrict__ hb, int n_nodes)
{
    // ---- Phase A: 1-pass histogram ----
    {
        const int gsz = (int)gridDim.x * 256;            // 524288
        for (int e = (int)blockIdx.x * 256 + (int)threadIdx.x; e < N_EDGES_C; e += gsz)
            atomicAdd(&cnt[dst[e]], 1);
    }
    // ---- Phase B: projection ----
    __shared__ float frow[4][IN_F];
    const int t = threadIdx.x;
    const int o = t >> 2;
    const int k = t & 3;
    float wreg[IN_F];
    {
        const float4* W4 = reinterpret_cast<const float4*>(W + (size_t)(k * OUT_F + o) * IN_F);
        #pragma unroll
        for (int i = 0; i < IN_F / 4; ++i) {
            float4 v = W4[i];
            wreg[4*i+0] = v.x; wreg[4*i+1] = v.y; wreg[4*i+2] = v.z; wreg[4*i+3] = v.w;
        }
    }
    const int nn4 = n_nodes >> 2;   // 25000
    for (int q = blockIdx.x; q < nn4; q += gridDim.x) {
        const int n0 = q << 2;
        if (t < 64) {
            float4 v = reinterpret_cast<const float4*>(feat + (size_t)n0 * IN_F)[t];
            reinterpret_cast<float4*>(frow[t >> 4])[t & 15] = v;
        }
        __syncthreads();
        const float4* f0 = reinterpret_cast<const float4*>(frow[0]);
        const float4* f1 = reinterpret_cast<const float4*>(frow[1]);
        const float4* f2 = reinterpret_cast<const float4*>(frow[2]);
        const float4* f3 = reinterpret_cast<const float4*>(frow[3]);
        float a0 = 0.f, a1 = 0.f, a2 = 0.f, a3 = 0.f;
        #pragma unroll
        for (int i = 0; i < IN_F / 4; ++i) {
            const float4 v0 = f0[i], v1 = f1[i], v2 = f2[i], v3 = f3[i];
            const float w0 = wreg[4*i], w1 = wreg[4*i+1], w2 = wreg[4*i+2], w3 = wreg[4*i+3];
            a0 = fmaf(v0.x,w0, fmaf(v0.y,w1, fmaf(v0.z,w2, fmaf(v0.w,w3, a0))));
            a1 = fmaf(v1.x,w0, fmaf(v1.y,w1, fmaf(v1.z,w2, fmaf(v1.w,w3, a1))));
            a2 = fmaf(v2.x,w0, fmaf(v2.y,w1, fmaf(v2.z,w2, fmaf(v2.w,w3, a2))));
            a3 = fmaf(v3.x,w0, fmaf(v3.y,w1, fmaf(v3.z,w2, fmaf(v3.w,w3, a3))));
        }
        hb[(size_t)(n0+0) * 256 + t] = (unsigned short)f2bf(a0);
        hb[(size_t)(n0+1) * 256 + t] = (unsigned short)f2bf(a1);
        hb[(size_t)(n0+2) * 256 + t] = (unsigned short)f2bf(a2);
        hb[(size_t)(n0+3) * 256 + t] = (unsigned short)f2bf(a3);
        __syncthreads();
    }
}

// ---------------------------------------------------------------------------
// scan1: per-block sums of cnt
// ---------------------------------------------------------------------------
__global__ __launch_bounds__(256) void scan1_kernel(
    const int* __restrict__ cnt, int* __restrict__ bsum)
{
    __shared__ int s[SCAN_BLK];
    int i = blockIdx.x * SCAN_BLK + threadIdx.x;
    int v = (i < N_NODES_C) ? cnt[i] : 0;
    s[threadIdx.x] = v; __syncthreads();
    for (int off = SCAN_BLK / 2; off > 0; off >>= 1) {
        if (threadIdx.x < off) s[threadIdx.x] += s[threadIdx.x + off];
        __syncthreads();
    }
    if (threadIdx.x == 0) bsum[blockIdx.x] = s[0];
}

// ---------------------------------------------------------------------------
// scan23: block-prefix over bsum + local exclusive scan -> row_start,
// padded cursor (one counter per 64B line)
// ---------------------------------------------------------------------------
__global__ __launch_bounds__(256) void scan23_kernel(
    const int* __restrict__ cnt, const int* __restrict__ bsum,
    int* __restrict__ row_start, int* __restrict__ cursor_pad)
{
    __shared__ int pre[SCAN_BLK];
    __shared__ int s[SCAN_BLK];
    const int t = threadIdx.x;
    int p = 0;
    for (int i = t; i < (int)blockIdx.x; i += SCAN_BLK) p += bsum[i];
    pre[t] = p; __syncthreads();
    for (int off = SCAN_BLK / 2; off > 0; off >>= 1) {
        if (t < off) pre[t] += pre[t + off];
        __syncthreads();
    }
    const int boff = pre[0];
    const int i = blockIdx.x * SCAN_BLK + t;
    int v = (i < N_NODES_C) ? cnt[i] : 0;
    s[t] = v; __syncthreads();
    for (int off = 1; off < SCAN_BLK; off <<= 1) {
        int x = (t >= off) ? s[t - off] : 0;
        __syncthreads();
        s[t] += x;
        __syncthreads();
    }
    if (i < N_NODES_C) {
        int ex = s[t] - v + boff;
        row_start[i] = ex;
        cursor_pad[(size_t)i * CPAD] = ex;
        if (i == N_NODES_C - 1) row_start[N_NODES_C] = ex + v;
    }
}

// ---------------------------------------------------------------------------
// scatter (gauss fused, XCD-sliced): block b handles dst-slice b&7; computes
// g for matching lanes, cursor atomic + 16B rec store stay XCD-local.
// ---------------------------------------------------------------------------
__global__ __launch_bounds__(256) void scatter_kernel(
    const int* __restrict__ src, const int* __restrict__ dst,
    const float* __restrict__ pseudo, const float* __restrict__ mu,
    const float* __restrict__ inv_sigma, int* __restrict__ cursor_pad,
    uint4* __restrict__ rec)
{
    float mm[NK*3], ss[NK*3];
    #pragma unroll
    for (int i = 0; i < NK*3; ++i) { mm[i] = mu[i]; ss[i] = inv_sigma[i]; }
    const int slice = (int)blockIdx.x & 7;
    const int w     = (int)blockIdx.x >> 3;          // 0..255 within slice
    const int lo = slice * SLICE_N, hi = lo + SLICE_N;
    for (int c = w; c < EBLK; c += SCAT_GRID / NSLICE) {
        const int e = c * 256 + (int)threadIdx.x;
        const int d = dst[e];
        if (d >= lo && d < hi) {
            const float p0 = pseudo[(size_t)e * 3 + 0];
            const float p1 = pseudo[(size_t)e * 3 + 1];
            const float p2 = pseudo[(size_t)e * 3 + 2];
            float g[NK];
            #pragma unroll
            for (int k = 0; k < NK; ++k) {
                const float d0 = p0 - mm[k*3+0], d1 = p1 - mm[k*3+1], d2 = p2 - mm[k*3+2];
                const float s0 = ss[k*3+0], s1 = ss[k*3+1], s2 = ss[k*3+2];
                g[k] = __expf(-0.5f * (d0*d0*s0*s0 + d1*d1*s1*s1 + d2*d2*s2*s2));
            }
            const int pos = atomicAdd(&cursor_pad[(size_t)d * CPAD], 1);
            uint4 r;
            r.x = (unsigned int)src[e];
            r.y = f2bf(g[0]) | (f2bf(g[1]) << 16);
            r.z = f2bf(g[2]) | (f2bf(g[3]) << 16);
            r.w = 0u;
            rec[pos] = r;
        }
    }
}

// ---------------------------------------------------------------------------
// gather: one wave per dst node (pipelined; at structural floor:
// 400MB L2-miss traffic mandatory = 8 XCD x 51.2MB hb at ~3.65 TB/s fabric)
// ---------------------------------------------------------------------------
__global__ __launch_bounds__(256, 2) void gather_kernel(
    const int* __restrict__ row_start, const uint4* __restrict__ rec,
    const unsigned short* __restrict__ hb,
    const float* __restrict__ feat, const float* __restrict__ bias,
    float* __restrict__ out, int n_nodes)
{
    const int lane = threadIdx.x & 63;
    const int v = (blockIdx.x * 256 + threadIdx.x) >> 6;
    if (v >= n_nodes) return;
    const int r0 = row_start[v];
    const int r1 = row_start[v + 1];
    float acc = 0.f;
    int j = r0;
    const int jend4 = r0 + ((r1 - r0) & ~3);
    if (j < jend4) {
        uint4 a0 = rec[j+0], a1 = rec[j+1], a2 = rec[j+2], a3 = rec[j+3];
        j += 4;
        for (; j < jend4; j += 4) {
            const uint2 h0 = *(const uint2*)(hb + (size_t)a0.x * 256 + lane * 4);
            const uint2 h1 = *(const uint2*)(hb + (size_t)a1.x * 256 + lane * 4);
            const uint2 h2 = *(const uint2*)(hb + (size_t)a2.x * 256 + lane * 4);
            const uint2 h3 = *(const uint2*)(hb + (size_t)a3.x * 256 + lane * 4);
            const uint4 b0 = rec[j+0], b1 = rec[j+1], b2 = rec[j+2], b3 = rec[j+3];
            acc += bflo(a0.y)*bflo(h0.x) + bfhi(a0.y)*bfhi(h0.x)
                 + bflo(a0.z)*bflo(h0.y) + bfhi(a0.z)*bfhi(h0.y);
            acc += bflo(a1.y)*bflo(h1.x) + bfhi(a1.y)*bfhi(h1.x)
                 + bflo(a1.z)*bflo(h1.y) + bfhi(a1.z)*bfhi(h1.y);
            acc += bflo(a2.y)*bflo(h2.x) + bfhi(a2.y)*bfhi(h2.x)
                 + bflo(a2.z)*bflo(h2.y) + bfhi(a2.z)*bfhi(h2.y);
            acc += bflo(a3.y)*bflo(h3.x) + bfhi(a3.y)*bfhi(h3.x)
                 + bflo(a3.z)*bflo(h3.y) + bfhi(a3.z)*bfhi(h3.y);
            a0 = b0; a1 = b1; a2 = b2; a3 = b3;
        }
        {
            const uint2 h0 = *(const uint2*)(hb + (size_t)a0.x * 256 + lane * 4);
            const uint2 h1 = *(const uint2*)(hb + (size_t)a1.x * 256 + lane * 4);
            const uint2 h2 = *(const uint2*)(hb + (size_t)a2.x * 256 + lane * 4);
            const uint2 h3 = *(const uint2*)(hb + (size_t)a3.x * 256 + lane * 4);
            acc += bflo(a0.y)*bflo(h0.x) + bfhi(a0.y)*bfhi(h0.x)
                 + bflo(a0.z)*bflo(h0.y) + bfhi(a0.z)*bfhi(h0.y);
            acc += bflo(a1.y)*bflo(h1.x) + bfhi(a1.y)*bfhi(h1.x)
                 + bflo(a1.z)*bflo(h1.y) + bfhi(a1.z)*bfhi(h1.y);
            acc += bflo(a2.y)*bflo(h2.x) + bfhi(a2.y)*bfhi(h2.x)
                 + bflo(a2.z)*bflo(h2.y) + bfhi(a2.z)*bfhi(h2.y);
            acc += bflo(a3.y)*bflo(h3.x) + bfhi(a3.y)*bfhi(h3.x)
                 + bflo(a3.z)*bflo(h3.y) + bfhi(a3.z)*bfhi(h3.y);
        }
    }
    for (; j < r1; ++j) {
        const uint4 ra = rec[j];
        const uint2 ha = *(const uint2*)(hb + (size_t)ra.x * 256 + lane * 4);
        acc += bflo(ra.y)*bflo(ha.x) + bfhi(ra.y)*bfhi(ha.x)
             + bflo(ra.z)*bflo(ha.y) + bfhi(ra.z)*bfhi(ha.y);
    }
    out[(size_t)v * OUT_F + lane] = acc + feat[(size_t)v * OUT_F + lane] + bias[lane];
}

extern "C" void kernel_launch(void* const* d_in, const int* in_sizes, int n_in,
                              void* d_out, int out_size, void* d_ws, size_t ws_size,
                              hipStream_t stream) {
    const float* feat      = (const float*)d_in[0];
    const float* pseudo    = (const float*)d_in[1];
    const int*   src       = (const int*)d_in[2];
    const int*   dst       = (const int*)d_in[3];
    const float* W_fc      = (const float*)d_in[4];
    const float* mu        = (const float*)d_in[5];
    const float* inv_sigma = (const float*)d_in[6];
    const float* bias      = (const float*)d_in[7];
    float* out = (float*)d_out;

    char* ws = (char*)d_ws;
    unsigned short* hb = (unsigned short*)ws;  ws += (size_t)N_NODES_C * 256 * 2;     // 51.2 MB
    uint4* rec         = (uint4*)ws;           ws += (size_t)N_EDGES_C * 16;          // 25.6 MB
    int* cursor_pad    = (int*)ws;             ws += (size_t)N_NODES_C * CPAD * 4;    // 6.4 MB
    int* cnt           = (int*)ws;             ws += (size_t)N_NODES_C * 4;           // 0.4 MB
    int* row_start     = (int*)ws;             ws += (size_t)(N_NODES_C + 4) * 4;     // 0.4 MB
    int* bsum          = (int*)ws;             ws += 512 * 4;

    hipMemsetAsync(cnt, 0, (size_t)N_NODES_C * 4, stream);
    proj_hist_kernel<<<SCAT_GRID, 256, 0, stream>>>(dst, cnt, feat, W_fc, hb, N_NODES_C);
    scan1_kernel<<<NBLK, SCAN_BLK, 0, stream>>>(cnt, bsum);
    scan23_kernel<<<NBLK, SCAN_BLK, 0, stream>>>(cnt, bsum, row_start, cursor_pad);
    scatter_kernel<<<SCAT_GRID, 256, 0, stream>>>(src, dst, pseudo, mu, inv_sigma,
                                                  cursor_pad, rec);
    gather_kernel<<<(N_NODES_C * 64 + 255) / 256, 256, 0, stream>>>(
        row_start, rec, hb, feat, bias, out, N_NODES_C);
}

// Round 20
// 286.109 us; speedup vs baseline: 1.2041x; 1.1220x over previous
//
#include <hip/hip_runtime.h>

#define N_NODES_C 100000
#define N_EDGES_C 1600000
#define IN_F 64
#define OUT_F 64
#define NK 4
#define SCAN_BLK 256
#define NBLK ((N_NODES_C + SCAN_BLK - 1) / SCAN_BLK)   // 391
#define EBLK (N_EDGES_C / 256)                         // 6250 exact
#define CPAD 16                                        // cursor stride: 1 per 64B line
#define NSLICE 8
#define SLICE_N (N_NODES_C / NSLICE)                   // 12500 exact
#define SCAT_GRID 2048                                 // 256 blocks per slice

typedef __attribute__((ext_vector_type(8))) short bf16x8;
typedef __attribute__((ext_vector_type(4))) float f32x4;

__device__ __forceinline__ unsigned int f2bf(float x) {
    unsigned int u = __float_as_uint(x);
    return (u + 0x7fffu + ((u >> 16) & 1u)) >> 16;
}
__device__ __forceinline__ float bflo(unsigned int u) { return __uint_as_float(u << 16); }
__device__ __forceinline__ float bfhi(unsigned int u) { return __uint_as_float(u & 0xffff0000u); }

__device__ __forceinline__ bf16x8 cvt8(const float4 a, const float4 b) {
    bf16x8 r;
    r[0]=(short)f2bf(a.x); r[1]=(short)f2bf(a.y); r[2]=(short)f2bf(a.z); r[3]=(short)f2bf(a.w);
    r[4]=(short)f2bf(b.x); r[5]=(short)f2bf(b.y); r[6]=(short)f2bf(b.z); r[7]=(short)f2bf(b.w);
    return r;
}

// ---------------------------------------------------------------------------
// proj_hist (fused, R17/R19 structure):
// Phase A: 1-pass grid-stride fire-and-forget hist.
// Phase B: MFMA proj — [100000x64]@[64x256] via mfma_f32_16x16x32_bf16.
//   Block = 4 waves; wave wv owns cols wv*64..+63 (4 col-tiles of 16).
//   B frags (W, bf16) loop-invariant in regs (32 VGPR); A = 2 float4 + cvt.
//   No LDS, no wreg[64] -> nothing for the allocator to rematerialize.
//   C/D layout per verified m89: col=lane&15, row=(lane>>4)*4+reg.
// ---------------------------------------------------------------------------
__global__ __launch_bounds__(256, 2) void proj_hist_kernel(
    const int* __restrict__ dst, int* __restrict__ cnt,
    const float* __restrict__ feat, const float* __restrict__ W,
    unsigned short* __restrict__ hb, int n_nodes)
{
    // ---- Phase A: 1-pass histogram ----
    {
        const int gsz = (int)gridDim.x * 256;            // 524288
        for (int e = (int)blockIdx.x * 256 + (int)threadIdx.x; e < N_EDGES_C; e += gsz)
            atomicAdd(&cnt[dst[e]], 1);
    }
    // ---- Phase B: MFMA projection ----
    const int t  = threadIdx.x;
    const int wv = t >> 6;          // wave 0..3 -> col strip
    const int l  = t & 63;
    const int lr = l & 15;          // A-row / B-col / D-col within tile
    const int lk = l >> 4;          // k-group 0..3 (8 contiguous k each)

    bf16x8 bfrag[4][2];
    #pragma unroll
    for (int tile = 0; tile < 4; ++tile) {
        const int col  = wv * 64 + tile * 16 + lr;
        const int wrow = (col & 3) * 64 + (col >> 2);    // W_fc row for this col
        #pragma unroll
        for (int ks = 0; ks < 2; ++ks) {
            const float4* wp = reinterpret_cast<const float4*>(
                W + (size_t)wrow * IN_F + ks * 32 + lk * 8);
            bfrag[tile][ks] = cvt8(wp[0], wp[1]);
        }
    }
    const int ntile = n_nodes >> 4;  // 6250
    for (int q = blockIdx.x; q < ntile; q += gridDim.x) {
        const int n0 = q << 4;
        const float4* ap = reinterpret_cast<const float4*>(
            feat + (size_t)(n0 + lr) * IN_F + lk * 8);
        const float4* aq = reinterpret_cast<const float4*>(
            feat + (size_t)(n0 + lr) * IN_F + 32 + lk * 8);
        const bf16x8 a0 = cvt8(ap[0], ap[1]);
        const bf16x8 a1 = cvt8(aq[0], aq[1]);
        #pragma unroll
        for (int tile = 0; tile < 4; ++tile) {
            f32x4 acc = {0.f, 0.f, 0.f, 0.f};
            acc = __builtin_amdgcn_mfma_f32_16x16x32_bf16(a0, bfrag[tile][0], acc, 0, 0, 0);
            acc = __builtin_amdgcn_mfma_f32_16x16x32_bf16(a1, bfrag[tile][1], acc, 0, 0, 0);
            const int col = wv * 64 + tile * 16 + lr;
            #pragma unroll
            for (int r = 0; r < 4; ++r)
                hb[(size_t)(n0 + lk * 4 + r) * 256 + col] = (unsigned short)f2bf(acc[r]);
        }
    }
}

// ---------------------------------------------------------------------------
// scan1: per-block sums of cnt
// ---------------------------------------------------------------------------
__global__ __launch_bounds__(256) void scan1_kernel(
    const int* __restrict__ cnt, int* __restrict__ bsum)
{
    __shared__ int s[SCAN_BLK];
    int i = blockIdx.x * SCAN_BLK + threadIdx.x;
    int v = (i < N_NODES_C) ? cnt[i] : 0;
    s[threadIdx.x] = v; __syncthreads();
    for (int off = SCAN_BLK / 2; off > 0; off >>= 1) {
        if (threadIdx.x < off) s[threadIdx.x] += s[threadIdx.x + off];
        __syncthreads();
    }
    if (threadIdx.x == 0) bsum[blockIdx.x] = s[0];
}

// ---------------------------------------------------------------------------
// scan23: block-prefix over bsum + local exclusive scan -> row_start,
// padded cursor (one counter per 64B line)
// ---------------------------------------------------------------------------
__global__ __launch_bounds__(256) void scan23_kernel(
    const int* __restrict__ cnt, const int* __restrict__ bsum,
    int* __restrict__ row_start, int* __restrict__ cursor_pad)
{
    __shared__ int pre[SCAN_BLK];
    __shared__ int s[SCAN_BLK];
    const int t = threadIdx.x;
    int p = 0;
    for (int i = t; i < (int)blockIdx.x; i += SCAN_BLK) p += bsum[i];
    pre[t] = p; __syncthreads();
    for (int off = SCAN_BLK / 2; off > 0; off >>= 1) {
        if (t < off) pre[t] += pre[t + off];
        __syncthreads();
    }
    const int boff = pre[0];
    const int i = blockIdx.x * SCAN_BLK + t;
    int v = (i < N_NODES_C) ? cnt[i] : 0;
    s[t] = v; __syncthreads();
    for (int off = 1; off < SCAN_BLK; off <<= 1) {
        int x = (t >= off) ? s[t - off] : 0;
        __syncthreads();
        s[t] += x;
        __syncthreads();
    }
    if (i < N_NODES_C) {
        int ex = s[t] - v + boff;
        row_start[i] = ex;
        cursor_pad[(size_t)i * CPAD] = ex;
        if (i == N_NODES_C - 1) row_start[N_NODES_C] = ex + v;
    }
}

// ---------------------------------------------------------------------------
// scatter (gauss fused, XCD-sliced): block b handles dst-slice b&7; computes
// g for matching lanes, cursor atomic + 16B rec store stay XCD-local.
// ---------------------------------------------------------------------------
__global__ __launch_bounds__(256) void scatter_kernel(
    const int* __restrict__ src, const int* __restrict__ dst,
    const float* __restrict__ pseudo, const float* __restrict__ mu,
    const float* __restrict__ inv_sigma, int* __restrict__ cursor_pad,
    uint4* __restrict__ rec)
{
    float mm[NK*3], ss[NK*3];
    #pragma unroll
    for (int i = 0; i < NK*3; ++i) { mm[i] = mu[i]; ss[i] = inv_sigma[i]; }
    const int slice = (int)blockIdx.x & 7;
    const int w     = (int)blockIdx.x >> 3;          // 0..255 within slice
    const int lo = slice * SLICE_N, hi = lo + SLICE_N;
    for (int c = w; c < EBLK; c += SCAT_GRID / NSLICE) {
        const int e = c * 256 + (int)threadIdx.x;
        const int d = dst[e];
        if (d >= lo && d < hi) {
            const float p0 = pseudo[(size_t)e * 3 + 0];
            const float p1 = pseudo[(size_t)e * 3 + 1];
            const float p2 = pseudo[(size_t)e * 3 + 2];
            float g[NK];
            #pragma unroll
            for (int k = 0; k < NK; ++k) {
                const float d0 = p0 - mm[k*3+0], d1 = p1 - mm[k*3+1], d2 = p2 - mm[k*3+2];
                const float s0 = ss[k*3+0], s1 = ss[k*3+1], s2 = ss[k*3+2];
                g[k] = __expf(-0.5f * (d0*d0*s0*s0 + d1*d1*s1*s1 + d2*d2*s2*s2));
            }
            const int pos = atomicAdd(&cursor_pad[(size_t)d * CPAD], 1);
            uint4 r;
            r.x = (unsigned int)src[e];
            r.y = f2bf(g[0]) | (f2bf(g[1]) << 16);
            r.z = f2bf(g[2]) | (f2bf(g[3]) << 16);
            r.w = 0u;
            rec[pos] = r;
        }
    }
}

// ---------------------------------------------------------------------------
// gather: one wave per dst node (pipelined; at structural floor:
// 400MB L2-miss traffic mandatory = 8 XCD x 51.2MB hb at ~3.65 TB/s fabric)
// ---------------------------------------------------------------------------
__global__ __launch_bounds__(256, 2) void gather_kernel(
    const int* __restrict__ row_start, const uint4* __restrict__ rec,
    const unsigned short* __restrict__ hb,
    const float* __restrict__ feat, const float* __restrict__ bias,
    float* __restrict__ out, int n_nodes)
{
    const int lane = threadIdx.x & 63;
    const int v = (blockIdx.x * 256 + threadIdx.x) >> 6;
    if (v >= n_nodes) return;
    const int r0 = row_start[v];
    const int r1 = row_start[v + 1];
    float acc = 0.f;
    int j = r0;
    const int jend4 = r0 + ((r1 - r0) & ~3);
    if (j < jend4) {
        uint4 a0 = rec[j+0], a1 = rec[j+1], a2 = rec[j+2], a3 = rec[j+3];
        j += 4;
        for (; j < jend4; j += 4) {
            const uint2 h0 = *(const uint2*)(hb + (size_t)a0.x * 256 + lane * 4);
            const uint2 h1 = *(const uint2*)(hb + (size_t)a1.x * 256 + lane * 4);
            const uint2 h2 = *(const uint2*)(hb + (size_t)a2.x * 256 + lane * 4);
            const uint2 h3 = *(const uint2*)(hb + (size_t)a3.x * 256 + lane * 4);
            const uint4 b0 = rec[j+0], b1 = rec[j+1], b2 = rec[j+2], b3 = rec[j+3];
            acc += bflo(a0.y)*bflo(h0.x) + bfhi(a0.y)*bfhi(h0.x)
                 + bflo(a0.z)*bflo(h0.y) + bfhi(a0.z)*bfhi(h0.y);
            acc += bflo(a1.y)*bflo(h1.x) + bfhi(a1.y)*bfhi(h1.x)
                 + bflo(a1.z)*bflo(h1.y) + bfhi(a1.z)*bfhi(h1.y);
            acc += bflo(a2.y)*bflo(h2.x) + bfhi(a2.y)*bfhi(h2.x)
                 + bflo(a2.z)*bflo(h2.y) + bfhi(a2.z)*bfhi(h2.y);
            acc += bflo(a3.y)*bflo(h3.x) + bfhi(a3.y)*bfhi(h3.x)
                 + bflo(a3.z)*bflo(h3.y) + bfhi(a3.z)*bfhi(h3.y);
            a0 = b0; a1 = b1; a2 = b2; a3 = b3;
        }
        {
            const uint2 h0 = *(const uint2*)(hb + (size_t)a0.x * 256 + lane * 4);
            const uint2 h1 = *(const uint2*)(hb + (size_t)a1.x * 256 + lane * 4);
            const uint2 h2 = *(const uint2*)(hb + (size_t)a2.x * 256 + lane * 4);
            const uint2 h3 = *(const uint2*)(hb + (size_t)a3.x * 256 + lane * 4);
            acc += bflo(a0.y)*bflo(h0.x) + bfhi(a0.y)*bfhi(h0.x)
                 + bflo(a0.z)*bflo(h0.y) + bfhi(a0.z)*bfhi(h0.y);
            acc += bflo(a1.y)*bflo(h1.x) + bfhi(a1.y)*bfhi(h1.x)
                 + bflo(a1.z)*bflo(h1.y) + bfhi(a1.z)*bfhi(h1.y);
            acc += bflo(a2.y)*bflo(h2.x) + bfhi(a2.y)*bfhi(h2.x)
                 + bflo(a2.z)*bflo(h2.y) + bfhi(a2.z)*bfhi(h2.y);
            acc += bflo(a3.y)*bflo(h3.x) + bfhi(a3.y)*bfhi(h3.x)
                 + bflo(a3.z)*bflo(h3.y) + bfhi(a3.z)*bfhi(h3.y);
        }
    }
    for (; j < r1; ++j) {
        const uint4 ra = rec[j];
        const uint2 ha = *(const uint2*)(hb + (size_t)ra.x * 256 + lane * 4);
        acc += bflo(ra.y)*bflo(ha.x) + bfhi(ra.y)*bfhi(ha.x)
             + bflo(ra.z)*bflo(ha.y) + bfhi(ra.z)*bfhi(ha.y);
    }
    out[(size_t)v * OUT_F + lane] = acc + feat[(size_t)v * OUT_F + lane] + bias[lane];
}

extern "C" void kernel_launch(void* const* d_in, const int* in_sizes, int n_in,
                              void* d_out, int out_size, void* d_ws, size_t ws_size,
                              hipStream_t stream) {
    const float* feat      = (const float*)d_in[0];
    const float* pseudo    = (const float*)d_in[1];
    const int*   src       = (const int*)d_in[2];
    const int*   dst       = (const int*)d_in[3];
    const float* W_fc      = (const float*)d_in[4];
    const float* mu        = (const float*)d_in[5];
    const float* inv_sigma = (const float*)d_in[6];
    const float* bias      = (const float*)d_in[7];
    float* out = (float*)d_out;

    char* ws = (char*)d_ws;
    unsigned short* hb = (unsigned short*)ws;  ws += (size_t)N_NODES_C * 256 * 2;     // 51.2 MB
    uint4* rec         = (uint4*)ws;           ws += (size_t)N_EDGES_C * 16;          // 25.6 MB
    int* cursor_pad    = (int*)ws;             ws += (size_t)N_NODES_C * CPAD * 4;    // 6.4 MB
    int* cnt           = (int*)ws;             ws += (size_t)N_NODES_C * 4;           // 0.4 MB
    int* row_start     = (int*)ws;             ws += (size_t)(N_NODES_C + 4) * 4;     // 0.4 MB
    int* bsum          = (int*)ws;             ws += 512 * 4;

    hipMemsetAsync(cnt, 0, (size_t)N_NODES_C * 4, stream);
    proj_hist_kernel<<<SCAT_GRID, 256, 0, stream>>>(dst, cnt, feat, W_fc, hb, N_NODES_C);
    scan1_kernel<<<NBLK, SCAN_BLK, 0, stream>>>(cnt, bsum);
    scan23_kernel<<<NBLK, SCAN_BLK, 0, stream>>>(cnt, bsum, row_start, cursor_pad);
    scatter_kernel<<<SCAT_GRID, 256, 0, stream>>>(src, dst, pseudo, mu, inv_sigma,
                                                  cursor_pad, rec);
    gather_kernel<<<(N_NODES_C * 64 + 255) / 256, 256, 0, stream>>>(
        row_start, rec, hb, feat, bias, out, N_NODES_C);
}

// Round 21
// 285.454 us; speedup vs baseline: 1.2069x; 1.0023x over previous
//
#include <hip/hip_runtime.h>

#define N_NODES_C 100000
#define N_EDGES_C 1600000
#define IN_F 64
#define OUT_F 64
#define NK 4
#define SCAN_BLK 256
#define NBLK ((N_NODES_C + SCAN_BLK - 1) / SCAN_BLK)   // 391
#define EBLK (N_EDGES_C / 256)                         // 6250 exact
#define CPAD 16                                        // cursor stride: 1 per 64B line
#define NSLICE 8
#define SLICE_N (N_NODES_C / NSLICE)                   // 12500 exact
#define SCAT_GRID 2048                                 // 256 blocks per slice

typedef __attribute__((ext_vector_type(8))) short bf16x8;
typedef __attribute__((ext_vector_type(4))) float f32x4;

__device__ __forceinline__ unsigned int f2bf(float x) {
    unsigned int u = __float_as_uint(x);
    return (u + 0x7fffu + ((u >> 16) & 1u)) >> 16;
}
__device__ __forceinline__ float bflo(unsigned int u) { return __uint_as_float(u << 16); }
__device__ __forceinline__ float bfhi(unsigned int u) { return __uint_as_float(u & 0xffff0000u); }

__device__ __forceinline__ bf16x8 cvt8(const float4 a, const float4 b) {
    bf16x8 r;
    r[0]=(short)f2bf(a.x); r[1]=(short)f2bf(a.y); r[2]=(short)f2bf(a.z); r[3]=(short)f2bf(a.w);
    r[4]=(short)f2bf(b.x); r[5]=(short)f2bf(b.y); r[6]=(short)f2bf(b.z); r[7]=(short)f2bf(b.w);
    return r;
}

// ---------------------------------------------------------------------------
// proj_hist (fused):
// Phase A: 1-pass grid-stride fire-and-forget hist.
// Phase B: MFMA proj via mfma_f32_16x16x32_bf16, with LDS-staged output:
//   the 16x256 bf16 D-tile is written to LDS, then copied to hb as 512
//   contiguous uint4 stores (full 64B lines; halves writeback vs scattered
//   2B stores, 8x fewer store instructions).
// ---------------------------------------------------------------------------
__global__ __launch_bounds__(256, 2) void proj_hist_kernel(
    const int* __restrict__ dst, int* __restrict__ cnt,
    const float* __restrict__ feat, const float* __restrict__ W,
    unsigned short* __restrict__ hb, int n_nodes)
{
    // ---- Phase A: 1-pass histogram ----
    {
        const int gsz = (int)gridDim.x * 256;            // 524288
        for (int e = (int)blockIdx.x * 256 + (int)threadIdx.x; e < N_EDGES_C; e += gsz)
            atomicAdd(&cnt[dst[e]], 1);
    }
    // ---- Phase B: MFMA projection ----
    __shared__ unsigned short stage[16 * 256];           // 8 KB
    const int t  = threadIdx.x;
    const int wv = t >> 6;          // wave 0..3 -> col strip
    const int l  = t & 63;
    const int lr = l & 15;          // A-row / B-col / D-col within tile
    const int lk = l >> 4;          // k-group 0..3 (8 contiguous k each)

    bf16x8 bfrag[4][2];
    #pragma unroll
    for (int tile = 0; tile < 4; ++tile) {
        const int col  = wv * 64 + tile * 16 + lr;
        const int wrow = (col & 3) * 64 + (col >> 2);    // W_fc row for this col
        #pragma unroll
        for (int ks = 0; ks < 2; ++ks) {
            const float4* wp = reinterpret_cast<const float4*>(
                W + (size_t)wrow * IN_F + ks * 32 + lk * 8);
            bfrag[tile][ks] = cvt8(wp[0], wp[1]);
        }
    }
    const int ntile = n_nodes >> 4;  // 6250
    for (int q = blockIdx.x; q < ntile; q += gridDim.x) {
        const int n0 = q << 4;
        const float4* ap = reinterpret_cast<const float4*>(
            feat + (size_t)(n0 + lr) * IN_F + lk * 8);
        const float4* aq = reinterpret_cast<const float4*>(
            feat + (size_t)(n0 + lr) * IN_F + 32 + lk * 8);
        const bf16x8 a0 = cvt8(ap[0], ap[1]);
        const bf16x8 a1 = cvt8(aq[0], aq[1]);
        #pragma unroll
        for (int tile = 0; tile < 4; ++tile) {
            f32x4 acc = {0.f, 0.f, 0.f, 0.f};
            acc = __builtin_amdgcn_mfma_f32_16x16x32_bf16(a0, bfrag[tile][0], acc, 0, 0, 0);
            acc = __builtin_amdgcn_mfma_f32_16x16x32_bf16(a1, bfrag[tile][1], acc, 0, 0, 0);
            const int col = wv * 64 + tile * 16 + lr;
            #pragma unroll
            for (int r = 0; r < 4; ++r)
                stage[(lk * 4 + r) * 256 + col] = (unsigned short)f2bf(acc[r]);
        }
        __syncthreads();
        // coalesced copy: 16 rows x 512B = 512 uint4; thread t -> t, t+256
        {
            const uint4* sp = reinterpret_cast<const uint4*>(stage);
            uint4* dp = reinterpret_cast<uint4*>(hb + (size_t)n0 * 256);
            dp[t]       = sp[t];
            dp[t + 256] = sp[t + 256];
        }
        __syncthreads();
    }
}

// ---------------------------------------------------------------------------
// scan1: per-block sums of cnt
// ---------------------------------------------------------------------------
__global__ __launch_bounds__(256) void scan1_kernel(
    const int* __restrict__ cnt, int* __restrict__ bsum)
{
    __shared__ int s[SCAN_BLK];
    int i = blockIdx.x * SCAN_BLK + threadIdx.x;
    int v = (i < N_NODES_C) ? cnt[i] : 0;
    s[threadIdx.x] = v; __syncthreads();
    for (int off = SCAN_BLK / 2; off > 0; off >>= 1) {
        if (threadIdx.x < off) s[threadIdx.x] += s[threadIdx.x + off];
        __syncthreads();
    }
    if (threadIdx.x == 0) bsum[blockIdx.x] = s[0];
}

// ---------------------------------------------------------------------------
// scan23: block-prefix over bsum + local exclusive scan -> row_start,
// padded cursor (one counter per 64B line)
// ---------------------------------------------------------------------------
__global__ __launch_bounds__(256) void scan23_kernel(
    const int* __restrict__ cnt, const int* __restrict__ bsum,
    int* __restrict__ row_start, int* __restrict__ cursor_pad)
{
    __shared__ int pre[SCAN_BLK];
    __shared__ int s[SCAN_BLK];
    const int t = threadIdx.x;
    int p = 0;
    for (int i = t; i < (int)blockIdx.x; i += SCAN_BLK) p += bsum[i];
    pre[t] = p; __syncthreads();
    for (int off = SCAN_BLK / 2; off > 0; off >>= 1) {
        if (t < off) pre[t] += pre[t + off];
        __syncthreads();
    }
    const int boff = pre[0];
    const int i = blockIdx.x * SCAN_BLK + t;
    int v = (i < N_NODES_C) ? cnt[i] : 0;
    s[t] = v; __syncthreads();
    for (int off = 1; off < SCAN_BLK; off <<= 1) {
        int x = (t >= off) ? s[t - off] : 0;
        __syncthreads();
        s[t] += x;
        __syncthreads();
    }
    if (i < N_NODES_C) {
        int ex = s[t] - v + boff;
        row_start[i] = ex;
        cursor_pad[(size_t)i * CPAD] = ex;
        if (i == N_NODES_C - 1) row_start[N_NODES_C] = ex + v;
    }
}

// ---------------------------------------------------------------------------
// scatter (gauss fused, XCD-sliced): block b handles dst-slice b&7; computes
// g for matching lanes, cursor atomic + 16B rec store stay XCD-local.
// ---------------------------------------------------------------------------
__global__ __launch_bounds__(256) void scatter_kernel(
    const int* __restrict__ src, const int* __restrict__ dst,
    const float* __restrict__ pseudo, const float* __restrict__ mu,
    const float* __restrict__ inv_sigma, int* __restrict__ cursor_pad,
    uint4* __restrict__ rec)
{
    float mm[NK*3], ss[NK*3];
    #pragma unroll
    for (int i = 0; i < NK*3; ++i) { mm[i] = mu[i]; ss[i] = inv_sigma[i]; }
    const int slice = (int)blockIdx.x & 7;
    const int w     = (int)blockIdx.x >> 3;          // 0..255 within slice
    const int lo = slice * SLICE_N, hi = lo + SLICE_N;
    for (int c = w; c < EBLK; c += SCAT_GRID / NSLICE) {
        const int e = c * 256 + (int)threadIdx.x;
        const int d = dst[e];
        if (d >= lo && d < hi) {
            const float p0 = pseudo[(size_t)e * 3 + 0];
            const float p1 = pseudo[(size_t)e * 3 + 1];
            const float p2 = pseudo[(size_t)e * 3 + 2];
            float g[NK];
            #pragma unroll
            for (int k = 0; k < NK; ++k) {
                const float d0 = p0 - mm[k*3+0], d1 = p1 - mm[k*3+1], d2 = p2 - mm[k*3+2];
                const float s0 = ss[k*3+0], s1 = ss[k*3+1], s2 = ss[k*3+2];
                g[k] = __expf(-0.5f * (d0*d0*s0*s0 + d1*d1*s1*s1 + d2*d2*s2*s2));
            }
            const int pos = atomicAdd(&cursor_pad[(size_t)d * CPAD], 1);
            uint4 r;
            r.x = (unsigned int)src[e];
            r.y = f2bf(g[0]) | (f2bf(g[1]) << 16);
            r.z = f2bf(g[2]) | (f2bf(g[3]) << 16);
            r.w = 0u;
            rec[pos] = r;
        }
    }
}

// ---------------------------------------------------------------------------
// gather: one wave per dst node (pipelined; at structural floor:
// 400MB L2-miss traffic mandatory = 8 XCD x 51.2MB hb at ~3.65 TB/s fabric)
// ---------------------------------------------------------------------------
__global__ __launch_bounds__(256, 2) void gather_kernel(
    const int* __restrict__ row_start, const uint4* __restrict__ rec,
    const unsigned short* __restrict__ hb,
    const float* __restrict__ feat, const float* __restrict__ bias,
    float* __restrict__ out, int n_nodes)
{
    const int lane = threadIdx.x & 63;
    const int v = (blockIdx.x * 256 + threadIdx.x) >> 6;
    if (v >= n_nodes) return;
    const int r0 = row_start[v];
    const int r1 = row_start[v + 1];
    float acc = 0.f;
    int j = r0;
    const int jend4 = r0 + ((r1 - r0) & ~3);
    if (j < jend4) {
        uint4 a0 = rec[j+0], a1 = rec[j+1], a2 = rec[j+2], a3 = rec[j+3];
        j += 4;
        for (; j < jend4; j += 4) {
            const uint2 h0 = *(const uint2*)(hb + (size_t)a0.x * 256 + lane * 4);
            const uint2 h1 = *(const uint2*)(hb + (size_t)a1.x * 256 + lane * 4);
            const uint2 h2 = *(const uint2*)(hb + (size_t)a2.x * 256 + lane * 4);
            const uint2 h3 = *(const uint2*)(hb + (size_t)a3.x * 256 + lane * 4);
            const uint4 b0 = rec[j+0], b1 = rec[j+1], b2 = rec[j+2], b3 = rec[j+3];
            acc += bflo(a0.y)*bflo(h0.x) + bfhi(a0.y)*bfhi(h0.x)
                 + bflo(a0.z)*bflo(h0.y) + bfhi(a0.z)*bfhi(h0.y);
            acc += bflo(a1.y)*bflo(h1.x) + bfhi(a1.y)*bfhi(h1.x)
                 + bflo(a1.z)*bflo(h1.y) + bfhi(a1.z)*bfhi(h1.y);
            acc += bflo(a2.y)*bflo(h2.x) + bfhi(a2.y)*bfhi(h2.x)
                 + bflo(a2.z)*bflo(h2.y) + bfhi(a2.z)*bfhi(h2.y);
            acc += bflo(a3.y)*bflo(h3.x) + bfhi(a3.y)*bfhi(h3.x)
                 + bflo(a3.z)*bflo(h3.y) + bfhi(a3.z)*bfhi(h3.y);
            a0 = b0; a1 = b1; a2 = b2; a3 = b3;
        }
        {
            const uint2 h0 = *(const uint2*)(hb + (size_t)a0.x * 256 + lane * 4);
            const uint2 h1 = *(const uint2*)(hb + (size_t)a1.x * 256 + lane * 4);
            const uint2 h2 = *(const uint2*)(hb + (size_t)a2.x * 256 + lane * 4);
            const uint2 h3 = *(const uint2*)(hb + (size_t)a3.x * 256 + lane * 4);
            acc += bflo(a0.y)*bflo(h0.x) + bfhi(a0.y)*bfhi(h0.x)
                 + bflo(a0.z)*bflo(h0.y) + bfhi(a0.z)*bfhi(h0.y);
            acc += bflo(a1.y)*bflo(h1.x) + bfhi(a1.y)*bfhi(h1.x)
                 + bflo(a1.z)*bflo(h1.y) + bfhi(a1.z)*bfhi(h1.y);
            acc += bflo(a2.y)*bflo(h2.x) + bfhi(a2.y)*bfhi(h2.x)
                 + bflo(a2.z)*bflo(h2.y) + bfhi(a2.z)*bfhi(h2.y);
            acc += bflo(a3.y)*bflo(h3.x) + bfhi(a3.y)*bfhi(h3.x)
                 + bflo(a3.z)*bflo(h3.y) + bfhi(a3.z)*bfhi(h3.y);
        }
    }
    for (; j < r1; ++j) {
        const uint4 ra = rec[j];
        const uint2 ha = *(const uint2*)(hb + (size_t)ra.x * 256 + lane * 4);
        acc += bflo(ra.y)*bflo(ha.x) + bfhi(ra.y)*bfhi(ha.x)
             + bflo(ra.z)*bflo(ha.y) + bfhi(ra.z)*bfhi(ha.y);
    }
    out[(size_t)v * OUT_F + lane] = acc + feat[(size_t)v * OUT_F + lane] + bias[lane];
}

extern "C" void kernel_launch(void* const* d_in, const int* in_sizes, int n_in,
                              void* d_out, int out_size, void* d_ws, size_t ws_size,
                              hipStream_t stream) {
    const float* feat      = (const float*)d_in[0];
    const float* pseudo    = (const float*)d_in[1];
    const int*   src       = (const int*)d_in[2];
    const int*   dst       = (const int*)d_in[3];
    const float* W_fc      = (const float*)d_in[4];
    const float* mu        = (const float*)d_in[5];
    const float* inv_sigma = (const float*)d_in[6];
    const float* bias      = (const float*)d_in[7];
    float* out = (float*)d_out;

    char* ws = (char*)d_ws;
    unsigned short* hb = (unsigned short*)ws;  ws += (size_t)N_NODES_C * 256 * 2;     // 51.2 MB
    uint4* rec         = (uint4*)ws;           ws += (size_t)N_EDGES_C * 16;          // 25.6 MB
    int* cursor_pad    = (int*)ws;             ws += (size_t)N_NODES_C * CPAD * 4;    // 6.4 MB
    int* cnt           = (int*)ws;             ws += (size_t)N_NODES_C * 4;           // 0.4 MB
    int* row_start     = (int*)ws;             ws += (size_t)(N_NODES_C + 4) * 4;     // 0.4 MB
    int* bsum          = (int*)ws;             ws += 512 * 4;

    hipMemsetAsync(cnt, 0, (size_t)N_NODES_C * 4, stream);
    proj_hist_kernel<<<SCAT_GRID, 256, 0, stream>>>(dst, cnt, feat, W_fc, hb, N_NODES_C);
    scan1_kernel<<<NBLK, SCAN_BLK, 0, stream>>>(cnt, bsum);
    scan23_kernel<<<NBLK, SCAN_BLK, 0, stream>>>(cnt, bsum, row_start, cursor_pad);
    scatter_kernel<<<SCAT_GRID, 256, 0, stream>>>(src, dst, pseudo, mu, inv_sigma,
                                                  cursor_pad, rec);
    gather_kernel<<<(N_NODES_C * 64 + 255) / 256, 256, 0, stream>>>(
        row_start, rec, hb, feat, bias, out, N_NODES_C);
}